// Round 1
// baseline (2197.844 us; speedup 1.0000x reference)
//
#include <hip/hip_runtime.h>

#define N_NODES 100000
#define N_EDGES 1600000
#define IN_C 128
#define HID_C 64
#define OUT_C 32

// ---------------- degree / norm ----------------

__global__ void k_init_deg(int* __restrict__ deg) {
    int i = blockIdx.x * blockDim.x + threadIdx.x;
    if (i < N_NODES) deg[i] = 1;  // self-loop contributes 1
}

__global__ void k_count_deg(const int* __restrict__ dst, int* __restrict__ deg) {
    int e = blockIdx.x * blockDim.x + threadIdx.x;
    if (e < N_EDGES) atomicAdd(&deg[dst[e]], 1);
}

__global__ void k_dinv(const int* __restrict__ deg, float* __restrict__ dinv) {
    int i = blockIdx.x * blockDim.x + threadIdx.x;
    if (i < N_NODES) dinv[i] = rsqrtf((float)deg[i]);
}

// ---------------- layer 1: hs1 = dinv * (x @ W1); acc1 = hs1 ----------------

__global__ __launch_bounds__(256) void k_gemm1(const float* __restrict__ x,
                                               const float* __restrict__ W1,
                                               const float* __restrict__ dinv,
                                               float* __restrict__ hs1,
                                               float* __restrict__ acc1) {
    __shared__ float Ws[IN_C * HID_C];  // 32 KiB
    __shared__ float xs[4][IN_C];       // 2 KiB
    int tid = threadIdx.x;
    for (int j = tid; j < IN_C * HID_C; j += 256) Ws[j] = W1[j];
    __syncthreads();

    int r = tid >> 6;   // 0..3
    int c = tid & 63;   // 0..63
    // N_NODES divisible by 4
    for (int row0 = blockIdx.x * 4; row0 < N_NODES; row0 += gridDim.x * 4) {
        ((float*)xs)[tid]       = x[row0 * IN_C + tid];
        ((float*)xs)[tid + 256] = x[row0 * IN_C + tid + 256];
        __syncthreads();
        float sum = 0.f;
#pragma unroll
        for (int k = 0; k < IN_C; ++k) sum += xs[r][k] * Ws[k * HID_C + c];
        int row = row0 + r;
        float v = dinv[row] * sum;
        hs1[row * HID_C + c]  = v;
        acc1[row * HID_C + c] = v;
        __syncthreads();
    }
}

// ---------------- edge scatter layer 1: acc1[dst] += hs1[src] ----------------

__global__ __launch_bounds__(256) void k_scatter1(const int* __restrict__ src,
                                                  const int* __restrict__ dst,
                                                  const float* __restrict__ hs1,
                                                  float* __restrict__ acc1) {
    long long idx = (long long)blockIdx.x * blockDim.x + threadIdx.x;
    int e  = (int)(idx >> 4);        // 16 threads per edge
    int ch = ((int)idx & 15) << 2;   // 4 channels each
    if (e >= N_EDGES) return;
    int s = src[e];
    int d = dst[e];
    float4 v = *(const float4*)&hs1[s * HID_C + ch];
    float* o = &acc1[d * HID_C + ch];
    atomicAdd(o + 0, v.x);
    atomicAdd(o + 1, v.y);
    atomicAdd(o + 2, v.z);
    atomicAdd(o + 3, v.w);
}

// ------- layer 2: a1 = relu(dinv*acc1 + b1); hs2 = dinv*(a1@W2); out = hs2 -------

__global__ __launch_bounds__(256) void k_gemm2(const float* __restrict__ acc1,
                                               const float* __restrict__ W2,
                                               const float* __restrict__ b1,
                                               const float* __restrict__ dinv,
                                               float* __restrict__ hs2,
                                               float* __restrict__ out) {
    __shared__ float Ws[HID_C * OUT_C];  // 8 KiB
    __shared__ float as[8][HID_C];       // 2 KiB
    int tid = threadIdx.x;
    for (int j = tid; j < HID_C * OUT_C; j += 256) Ws[j] = W2[j];
    __syncthreads();

    int r = tid >> 5;   // 0..7
    int c = tid & 31;   // 0..31
    // N_NODES divisible by 8
    for (int row0 = blockIdx.x * 8; row0 < N_NODES; row0 += gridDim.x * 8) {
        int j = tid;
#pragma unroll
        for (int t = 0; t < 2; ++t, j += 256) {
            int rr = j >> 6, cc = j & 63;
            int row = row0 + rr;
            float v = dinv[row] * acc1[row * HID_C + cc] + b1[cc];
            as[rr][cc] = fmaxf(v, 0.f);
        }
        j = tid;
        __syncthreads();
        float sum = 0.f;
#pragma unroll
        for (int k = 0; k < HID_C; ++k) sum += as[r][k] * Ws[k * OUT_C + c];
        int row = row0 + r;
        float v = dinv[row] * sum;
        hs2[row * OUT_C + c] = v;
        out[row * OUT_C + c] = v;
        __syncthreads();
    }
}

// ---------------- edge scatter layer 2: out[dst] += hs2[src] ----------------

__global__ __launch_bounds__(256) void k_scatter2(const int* __restrict__ src,
                                                  const int* __restrict__ dst,
                                                  const float* __restrict__ hs2,
                                                  float* __restrict__ out) {
    long long idx = (long long)blockIdx.x * blockDim.x + threadIdx.x;
    int e  = (int)(idx >> 3);        // 8 threads per edge
    int ch = ((int)idx & 7) << 2;    // 4 channels each
    if (e >= N_EDGES) return;
    int s = src[e];
    int d = dst[e];
    float4 v = *(const float4*)&hs2[s * OUT_C + ch];
    float* o = &out[d * OUT_C + ch];
    atomicAdd(o + 0, v.x);
    atomicAdd(o + 1, v.y);
    atomicAdd(o + 2, v.z);
    atomicAdd(o + 3, v.w);
}

// ---------------- epilogue: out = dinv*out + b2 ----------------

__global__ void k_final(float* __restrict__ out, const float* __restrict__ b2,
                        const float* __restrict__ dinv) {
    int idx = blockIdx.x * blockDim.x + threadIdx.x;
    if (idx < N_NODES * OUT_C) {
        int row = idx >> 5;
        int c   = idx & 31;
        out[idx] = dinv[row] * out[idx] + b2[c];
    }
}

extern "C" void kernel_launch(void* const* d_in, const int* in_sizes, int n_in,
                              void* d_out, int out_size, void* d_ws, size_t ws_size,
                              hipStream_t stream) {
    const float* x  = (const float*)d_in[0];
    const int* ei   = (const int*)d_in[1];   // [2, E]: src then dst
    const float* W1 = (const float*)d_in[2];
    const float* b1 = (const float*)d_in[3];
    const float* W2 = (const float*)d_in[4];
    const float* b2 = (const float*)d_in[5];
    float* out = (float*)d_out;

    const int* src = ei;
    const int* dst = ei + N_EDGES;

    // workspace layout (bytes)
    char* ws = (char*)d_ws;
    int*   deg  = (int*)(ws + 0);                       // 400,000 B
    float* dinv = (float*)(ws + 400000);                // 400,000 B
    float* hs1  = (float*)(ws + 800000);                // 25.6 MB
    float* acc1 = (float*)(ws + 800000 + 25600000);     // 25.6 MB
    float* hs2  = (float*)(ws + 800000 + 51200000);     // 12.8 MB
    // total: 64.8 MB

    k_init_deg<<<(N_NODES + 255) / 256, 256, 0, stream>>>(deg);
    k_count_deg<<<(N_EDGES + 255) / 256, 256, 0, stream>>>(dst, deg);
    k_dinv<<<(N_NODES + 255) / 256, 256, 0, stream>>>(deg, dinv);

    k_gemm1<<<N_NODES / 4, 256, 0, stream>>>(x, W1, dinv, hs1, acc1);

    k_scatter1<<<(N_EDGES * 16) / 256, 256, 0, stream>>>(src, dst, hs1, acc1);

    k_gemm2<<<N_NODES / 8, 256, 0, stream>>>(acc1, W2, b1, dinv, hs2, out);

    k_scatter2<<<(N_EDGES * 8) / 256, 256, 0, stream>>>(src, dst, hs2, out);

    k_final<<<(N_NODES * OUT_C + 255) / 256, 256, 0, stream>>>(out, b2, dinv);
}

// Round 2
// 712.714 us; speedup vs baseline: 3.0838x; 3.0838x over previous
//
#include <hip/hip_runtime.h>

#define N_NODES 100000
#define N_EDGES 1600000
#define IN_C 128
#define HID_C 64
#define OUT_C 32

// ---------------- degree / norm ----------------

__global__ void k_init_deg(int* __restrict__ deg) {
    int i = blockIdx.x * blockDim.x + threadIdx.x;
    if (i < N_NODES) deg[i] = 1;  // self-loop contributes 1
}

__global__ void k_count_deg(const int* __restrict__ dst, int* __restrict__ deg) {
    int e = blockIdx.x * blockDim.x + threadIdx.x;
    if (e < N_EDGES) atomicAdd(&deg[dst[e]], 1);
}

__global__ void k_dinv(const int* __restrict__ deg, float* __restrict__ dinv) {
    int i = blockIdx.x * blockDim.x + threadIdx.x;
    if (i < N_NODES) dinv[i] = rsqrtf((float)deg[i]);
}

// ---------------- exclusive scan of (deg-1) -> row_start, cursor ----------------
// Single block, 1024 threads, each owns a 98-element chunk.

__global__ __launch_bounds__(1024) void k_scan(const int* __restrict__ deg,
                                               int* __restrict__ row_start,
                                               int* __restrict__ cursor) {
    __shared__ int sums[1024];
    const int CH = 98;  // 1024*98 = 100352 >= N_NODES+1
    int t = threadIdx.x;
    int base = t * CH;
    int s = 0;
    for (int k = 0; k < CH; ++k) {
        int i = base + k;
        if (i < N_NODES) s += deg[i] - 1;
    }
    sums[t] = s;
    __syncthreads();
    // Hillis-Steele inclusive scan over 1024 partials
    for (int off = 1; off < 1024; off <<= 1) {
        int v = (t >= off) ? sums[t - off] : 0;
        __syncthreads();
        sums[t] += v;
        __syncthreads();
    }
    int run = (t > 0) ? sums[t - 1] : 0;  // exclusive prefix for this chunk
    for (int k = 0; k < CH; ++k) {
        int i = base + k;
        if (i < N_NODES) {
            row_start[i] = run;
            cursor[i]    = run;
            run += deg[i] - 1;
        } else if (i == N_NODES) {
            row_start[i] = run;  // == N_EDGES
        }
    }
}

// ---------------- CSR bucket fill: eidx[pos] = src ----------------

__global__ void k_fill_csr(const int* __restrict__ src, const int* __restrict__ dst,
                           int* __restrict__ cursor, int* __restrict__ eidx) {
    int e = blockIdx.x * blockDim.x + threadIdx.x;
    if (e < N_EDGES) {
        int pos = atomicAdd(&cursor[dst[e]], 1);
        eidx[pos] = src[e];
    }
}

// ---------------- layer 1 GEMM: hs1 = dinv * (x @ W1) ----------------

__global__ __launch_bounds__(256) void k_gemm1(const float* __restrict__ x,
                                               const float* __restrict__ W1,
                                               const float* __restrict__ dinv,
                                               float* __restrict__ hs1) {
    __shared__ float Ws[IN_C * HID_C];  // 32 KiB
    __shared__ float xs[4][IN_C];       // 2 KiB
    int tid = threadIdx.x;
    for (int j = tid; j < IN_C * HID_C; j += 256) Ws[j] = W1[j];
    __syncthreads();

    int r = tid >> 6;   // 0..3
    int c = tid & 63;   // 0..63
    for (int row0 = blockIdx.x * 4; row0 < N_NODES; row0 += gridDim.x * 4) {
        ((float*)xs)[tid]       = x[row0 * IN_C + tid];
        ((float*)xs)[tid + 256] = x[row0 * IN_C + tid + 256];
        __syncthreads();
        float sum = 0.f;
#pragma unroll
        for (int k = 0; k < IN_C; ++k) sum += xs[r][k] * Ws[k * HID_C + c];
        int row = row0 + r;
        hs1[row * HID_C + c] = dinv[row] * sum;
        __syncthreads();
    }
}

// ------- gather layer 1 + epilogue: a1 = relu(dinv*(hs1[i] + sum_j hs1[src_j]) + b1) -------
// One wave (64 lanes) per node; lane = channel.

__global__ __launch_bounds__(256) void k_gather1(const int* __restrict__ row_start,
                                                 const int* __restrict__ eidx,
                                                 const float* __restrict__ hs1,
                                                 const float* __restrict__ dinv,
                                                 const float* __restrict__ b1,
                                                 float* __restrict__ a1) {
    int tid  = threadIdx.x;
    int lane = tid & 63;
    int node = blockIdx.x * 4 + (tid >> 6);
    if (node >= N_NODES) return;

    int rs = row_start[node];
    int re = row_start[node + 1];
    float acc = hs1[node * HID_C + lane];  // self loop
    int j = rs;
    for (; j + 3 < re; j += 4) {
        int s0 = eidx[j], s1 = eidx[j + 1], s2 = eidx[j + 2], s3 = eidx[j + 3];
        float v0 = hs1[s0 * HID_C + lane];
        float v1 = hs1[s1 * HID_C + lane];
        float v2 = hs1[s2 * HID_C + lane];
        float v3 = hs1[s3 * HID_C + lane];
        acc += v0 + v1 + v2 + v3;
    }
    for (; j < re; ++j) acc += hs1[eidx[j] * HID_C + lane];

    float v = dinv[node] * acc + b1[lane];
    a1[node * HID_C + lane] = fmaxf(v, 0.f);
}

// ---------------- layer 2 GEMM: hs2 = dinv * (a1 @ W2) ----------------

__global__ __launch_bounds__(256) void k_gemm2(const float* __restrict__ a1,
                                               const float* __restrict__ W2,
                                               const float* __restrict__ dinv,
                                               float* __restrict__ hs2) {
    __shared__ float Ws[HID_C * OUT_C];  // 8 KiB
    __shared__ float as[8][HID_C];       // 2 KiB
    int tid = threadIdx.x;
    for (int j = tid; j < HID_C * OUT_C; j += 256) Ws[j] = W2[j];
    __syncthreads();

    int r = tid >> 5;   // 0..7
    int c = tid & 31;   // 0..31
    for (int row0 = blockIdx.x * 8; row0 < N_NODES; row0 += gridDim.x * 8) {
        ((float*)as)[tid]       = a1[row0 * HID_C + tid];
        ((float*)as)[tid + 256] = a1[row0 * HID_C + tid + 256];
        __syncthreads();
        float sum = 0.f;
#pragma unroll
        for (int k = 0; k < HID_C; ++k) sum += as[r][k] * Ws[k * OUT_C + c];
        int row = row0 + r;
        hs2[row * OUT_C + c] = dinv[row] * sum;
        __syncthreads();
    }
}

// ------- gather layer 2 + epilogue: out = dinv*(hs2[i] + sum_j hs2[src_j]) + b2 -------
// One wave per node; lanes = 2 edges x 32 channels; __shfl_xor(32) combine.

__global__ __launch_bounds__(256) void k_gather2(const int* __restrict__ row_start,
                                                 const int* __restrict__ eidx,
                                                 const float* __restrict__ hs2,
                                                 const float* __restrict__ dinv,
                                                 const float* __restrict__ b2,
                                                 float* __restrict__ out) {
    int tid  = threadIdx.x;
    int lane = tid & 63;
    int half = lane >> 5;   // 0 or 1
    int c    = lane & 31;
    int node = blockIdx.x * 4 + (tid >> 6);
    if (node >= N_NODES) return;

    int rs = row_start[node];
    int re = row_start[node + 1];
    float acc = (half == 0) ? hs2[node * OUT_C + c] : 0.f;  // self loop
    int j = rs + half;
    for (; j + 3 < re; j += 4) {  // 2 edges/step per half, unrolled x2
        int s0 = eidx[j], s1 = eidx[j + 2];
        float v0 = hs2[s0 * OUT_C + c];
        float v1 = hs2[s1 * OUT_C + c];
        acc += v0 + v1;
    }
    for (; j < re; j += 2) acc += hs2[eidx[j] * OUT_C + c];

    acc += __shfl_xor(acc, 32);
    if (half == 0) out[node * OUT_C + c] = dinv[node] * acc + b2[c];
}

extern "C" void kernel_launch(void* const* d_in, const int* in_sizes, int n_in,
                              void* d_out, int out_size, void* d_ws, size_t ws_size,
                              hipStream_t stream) {
    const float* x  = (const float*)d_in[0];
    const int* ei   = (const int*)d_in[1];   // [2, E]: src then dst
    const float* W1 = (const float*)d_in[2];
    const float* b1 = (const float*)d_in[3];
    const float* W2 = (const float*)d_in[4];
    const float* b2 = (const float*)d_in[5];
    float* out = (float*)d_out;

    const int* src = ei;
    const int* dst = ei + N_EDGES;

    // workspace layout (bytes), total ~59.2 MB
    char* ws = (char*)d_ws;
    int*   deg       = (int*)(ws + 0);                    // 400 KB
    float* dinv      = (float*)(ws + 400000);             // 400 KB
    int*   row_start = (int*)(ws + 800000);               // 400 KB+4 (N+1)
    int*   cursor    = (int*)(ws + 1200004);              // 400 KB
    int*   eidx      = (int*)(ws + 1600004);              // 6.4 MB
    float* hs1       = (float*)(ws + 8000004);            // 25.6 MB
    float* a1        = (float*)(ws + 33600004);           // 25.6 MB
    float* hs2       = hs1;                               // reuse (hs1 dead after gather1)

    k_init_deg<<<(N_NODES + 255) / 256, 256, 0, stream>>>(deg);
    k_count_deg<<<(N_EDGES + 255) / 256, 256, 0, stream>>>(dst, deg);
    k_dinv<<<(N_NODES + 255) / 256, 256, 0, stream>>>(deg, dinv);

    k_scan<<<1, 1024, 0, stream>>>(deg, row_start, cursor);
    k_fill_csr<<<(N_EDGES + 255) / 256, 256, 0, stream>>>(src, dst, cursor, eidx);

    k_gemm1<<<N_NODES / 4, 256, 0, stream>>>(x, W1, dinv, hs1);
    k_gather1<<<N_NODES / 4, 256, 0, stream>>>(row_start, eidx, hs1, dinv, b1, a1);

    k_gemm2<<<N_NODES / 8, 256, 0, stream>>>(a1, W2, dinv, hs2);
    k_gather2<<<N_NODES / 4, 256, 0, stream>>>(row_start, eidx, hs2, dinv, b2, out);
}

// Round 3
// 462.662 us; speedup vs baseline: 4.7504x; 1.5405x over previous
//
#include <hip/hip_runtime.h>

#define N_NODES 100000
#define N_EDGES 1600000
#define IN_C 128
#define HID_C 64
#define OUT_C 32

#define SCAN_CHUNK 512
#define SCAN_NBLK 196  // ceil(N_NODES / SCAN_CHUNK)

// ---------------- degree ----------------

__global__ void k_init_deg(int* __restrict__ deg) {
    int i = blockIdx.x * blockDim.x + threadIdx.x;
    if (i < N_NODES) deg[i] = 1;  // self-loop contributes 1
}

__global__ void k_count_deg(const int* __restrict__ dst, int* __restrict__ deg) {
    int e = blockIdx.x * blockDim.x + threadIdx.x;
    if (e < N_EDGES) atomicAdd(&deg[dst[e]], 1);
}

// ---------------- device-wide exclusive scan of (deg-1), 3 phases ----------------

__global__ __launch_bounds__(256) void k_scan_sums(const int* __restrict__ deg,
                                                   int* __restrict__ blockSums) {
    __shared__ int red[256];
    int t = threadIdx.x;
    int base = blockIdx.x * SCAN_CHUNK;
    int s = 0;
    int i0 = base + t;
    if (i0 < N_NODES) s += deg[i0] - 1;
    int i1 = base + 256 + t;
    if (i1 < N_NODES) s += deg[i1] - 1;
    red[t] = s;
    __syncthreads();
    for (int off = 128; off > 0; off >>= 1) {
        if (t < off) red[t] += red[t + off];
        __syncthreads();
    }
    if (t == 0) blockSums[blockIdx.x] = red[0];
}

__global__ __launch_bounds__(256) void k_scan_offsets(const int* __restrict__ blockSums,
                                                      int* __restrict__ blockOff) {
    __shared__ int sums[256];
    int t = threadIdx.x;
    sums[t] = (t < SCAN_NBLK) ? blockSums[t] : 0;
    __syncthreads();
    for (int off = 1; off < 256; off <<= 1) {
        int v = (t >= off) ? sums[t - off] : 0;
        __syncthreads();
        sums[t] += v;
        __syncthreads();
    }
    blockOff[t] = (t > 0) ? sums[t - 1] : 0;  // exclusive
}

__global__ __launch_bounds__(256) void k_scan_final(const int* __restrict__ deg,
                                                    const int* __restrict__ blockOff,
                                                    int* __restrict__ row_start,
                                                    int* __restrict__ cursor,
                                                    float* __restrict__ dinv) {
    __shared__ int vals[SCAN_CHUNK];
    __shared__ int part[256];
    int t = threadIdx.x;
    int base = blockIdx.x * SCAN_CHUNK;
#pragma unroll
    for (int k = 0; k < 2; ++k) {
        int i = base + k * 256 + t;
        int d = (i < N_NODES) ? deg[i] : 1;
        vals[k * 256 + t] = d - 1;
        if (i < N_NODES) dinv[i] = rsqrtf((float)d);
    }
    __syncthreads();
    int a = vals[2 * t], b = vals[2 * t + 1];
    part[t] = a + b;
    __syncthreads();
    for (int off = 1; off < 256; off <<= 1) {
        int v = (t >= off) ? part[t - off] : 0;
        __syncthreads();
        part[t] += v;
        __syncthreads();
    }
    int ex = blockOff[blockIdx.x] + ((t > 0) ? part[t - 1] : 0);
    int i0 = base + 2 * t;
    int i1 = i0 + 1;
    if (i0 <= N_NODES) { row_start[i0] = ex; if (i0 < N_NODES) cursor[i0] = ex; }
    int ex1 = ex + a;
    if (i1 <= N_NODES) { row_start[i1] = ex1; if (i1 < N_NODES) cursor[i1] = ex1; }
}

// ---------------- CSR bucket fill: eidx[pos] = src ----------------

__global__ void k_fill_csr(const int* __restrict__ src, const int* __restrict__ dst,
                           int* __restrict__ cursor, int* __restrict__ eidx) {
    int e = blockIdx.x * blockDim.x + threadIdx.x;
    if (e < N_EDGES) {
        int pos = atomicAdd(&cursor[dst[e]], 1);
        eidx[pos] = src[e];
    }
}

// ---------------- layer 1 GEMM: hs1 = dinv * (x @ W1) ----------------

__global__ __launch_bounds__(256) void k_gemm1(const float* __restrict__ x,
                                               const float* __restrict__ W1,
                                               const float* __restrict__ dinv,
                                               float* __restrict__ hs1) {
    __shared__ float Ws[IN_C * HID_C];  // 32 KiB
    __shared__ float xs[4][IN_C];       // 2 KiB
    int tid = threadIdx.x;
    for (int j = tid; j < IN_C * HID_C; j += 256) Ws[j] = W1[j];
    __syncthreads();

    int r = tid >> 6;   // 0..3
    int c = tid & 63;   // 0..63
    for (int row0 = blockIdx.x * 4; row0 < N_NODES; row0 += gridDim.x * 4) {
        ((float*)xs)[tid]       = x[row0 * IN_C + tid];
        ((float*)xs)[tid + 256] = x[row0 * IN_C + tid + 256];
        __syncthreads();
        float sum = 0.f;
#pragma unroll
        for (int k = 0; k < IN_C; ++k) sum += xs[r][k] * Ws[k * HID_C + c];
        int row = row0 + r;
        hs1[row * HID_C + c] = dinv[row] * sum;
        __syncthreads();
    }
}

// ------- gather layer 1 + epilogue: a1 = relu(dinv*(hs1[i] + sum_j hs1[src_j]) + b1) -------

__global__ __launch_bounds__(256) void k_gather1(const int* __restrict__ row_start,
                                                 const int* __restrict__ eidx,
                                                 const float* __restrict__ hs1,
                                                 const float* __restrict__ dinv,
                                                 const float* __restrict__ b1,
                                                 float* __restrict__ a1) {
    int tid  = threadIdx.x;
    int lane = tid & 63;
    int node = blockIdx.x * 4 + (tid >> 6);
    if (node >= N_NODES) return;

    int rs = row_start[node];
    int re = row_start[node + 1];
    float acc = hs1[node * HID_C + lane];  // self loop
    int j = rs;
    for (; j + 3 < re; j += 4) {
        int s0 = eidx[j], s1 = eidx[j + 1], s2 = eidx[j + 2], s3 = eidx[j + 3];
        float v0 = hs1[s0 * HID_C + lane];
        float v1 = hs1[s1 * HID_C + lane];
        float v2 = hs1[s2 * HID_C + lane];
        float v3 = hs1[s3 * HID_C + lane];
        acc += v0 + v1 + v2 + v3;
    }
    for (; j < re; ++j) acc += hs1[eidx[j] * HID_C + lane];

    float v = dinv[node] * acc + b1[lane];
    a1[node * HID_C + lane] = fmaxf(v, 0.f);
}

// ---------------- layer 2 GEMM: hs2 = dinv * (a1 @ W2) ----------------

__global__ __launch_bounds__(256) void k_gemm2(const float* __restrict__ a1,
                                               const float* __restrict__ W2,
                                               const float* __restrict__ dinv,
                                               float* __restrict__ hs2) {
    __shared__ float Ws[HID_C * OUT_C];  // 8 KiB
    __shared__ float as[8][HID_C];       // 2 KiB
    int tid = threadIdx.x;
    for (int j = tid; j < HID_C * OUT_C; j += 256) Ws[j] = W2[j];
    __syncthreads();

    int r = tid >> 5;   // 0..7
    int c = tid & 31;   // 0..31
    for (int row0 = blockIdx.x * 8; row0 < N_NODES; row0 += gridDim.x * 8) {
        ((float*)as)[tid]       = a1[row0 * HID_C + tid];
        ((float*)as)[tid + 256] = a1[row0 * HID_C + tid + 256];
        __syncthreads();
        float sum = 0.f;
#pragma unroll
        for (int k = 0; k < HID_C; ++k) sum += as[r][k] * Ws[k * OUT_C + c];
        int row = row0 + r;
        hs2[row * OUT_C + c] = dinv[row] * sum;
        __syncthreads();
    }
}

// ------- gather layer 2 + epilogue: out = dinv*(hs2[i] + sum_j hs2[src_j]) + b2 -------

__global__ __launch_bounds__(256) void k_gather2(const int* __restrict__ row_start,
                                                 const int* __restrict__ eidx,
                                                 const float* __restrict__ hs2,
                                                 const float* __restrict__ dinv,
                                                 const float* __restrict__ b2,
                                                 float* __restrict__ out) {
    int tid  = threadIdx.x;
    int lane = tid & 63;
    int half = lane >> 5;   // 0 or 1
    int c    = lane & 31;
    int node = blockIdx.x * 4 + (tid >> 6);
    if (node >= N_NODES) return;

    int rs = row_start[node];
    int re = row_start[node + 1];
    float acc = (half == 0) ? hs2[node * OUT_C + c] : 0.f;  // self loop
    int j = rs + half;
    for (; j + 3 < re; j += 4) {
        int s0 = eidx[j], s1 = eidx[j + 2];
        float v0 = hs2[s0 * OUT_C + c];
        float v1 = hs2[s1 * OUT_C + c];
        acc += v0 + v1;
    }
    for (; j < re; j += 2) acc += hs2[eidx[j] * OUT_C + c];

    acc += __shfl_xor(acc, 32);
    if (half == 0) out[node * OUT_C + c] = dinv[node] * acc + b2[c];
}

extern "C" void kernel_launch(void* const* d_in, const int* in_sizes, int n_in,
                              void* d_out, int out_size, void* d_ws, size_t ws_size,
                              hipStream_t stream) {
    const float* x  = (const float*)d_in[0];
    const int* ei   = (const int*)d_in[1];   // [2, E]: src then dst
    const float* W1 = (const float*)d_in[2];
    const float* b1 = (const float*)d_in[3];
    const float* W2 = (const float*)d_in[4];
    const float* b2 = (const float*)d_in[5];
    float* out = (float*)d_out;

    const int* src = ei;
    const int* dst = ei + N_EDGES;

    // workspace layout (bytes), total ~59.2 MB
    char* ws = (char*)d_ws;
    int*   deg       = (int*)(ws + 0);                    // 400 KB
    float* dinv      = (float*)(ws + 400000);             // 400 KB
    int*   row_start = (int*)(ws + 800000);               // 400 KB + 4
    int*   cursor    = (int*)(ws + 1200004);              // 400 KB
    int*   blockSums = (int*)(ws + 1600004);              // 784 B
    int*   blockOff  = (int*)(ws + 1600788);              // 1 KB
    int*   eidx      = (int*)(ws + 1601812);              // 6.4 MB
    float* hs1       = (float*)(ws + 8001812);            // 25.6 MB
    float* a1        = (float*)(ws + 33601812);           // 25.6 MB
    float* hs2       = hs1;                               // reuse (hs1 dead after gather1)

    k_init_deg<<<(N_NODES + 255) / 256, 256, 0, stream>>>(deg);
    k_count_deg<<<(N_EDGES + 255) / 256, 256, 0, stream>>>(dst, deg);

    k_scan_sums<<<SCAN_NBLK, 256, 0, stream>>>(deg, blockSums);
    k_scan_offsets<<<1, 256, 0, stream>>>(blockSums, blockOff);
    k_scan_final<<<SCAN_NBLK, 256, 0, stream>>>(deg, blockOff, row_start, cursor, dinv);

    k_fill_csr<<<(N_EDGES + 255) / 256, 256, 0, stream>>>(src, dst, cursor, eidx);

    k_gemm1<<<N_NODES / 4, 256, 0, stream>>>(x, W1, dinv, hs1);
    k_gather1<<<N_NODES / 4, 256, 0, stream>>>(row_start, eidx, hs1, dinv, b1, a1);

    k_gemm2<<<N_NODES / 8, 256, 0, stream>>>(a1, W2, dinv, hs2);
    k_gather2<<<N_NODES / 4, 256, 0, stream>>>(row_start, eidx, hs2, dinv, b2, out);
}

// Round 4
// 291.857 us; speedup vs baseline: 7.5306x; 1.5852x over previous
//
#include <hip/hip_runtime.h>

#define N_NODES 100000
#define N_EDGES 1600000
#define IN_C 128
#define HID_C 64
#define OUT_C 32

#define NBUCK 782        // ceil(100000 / 128) buckets of 128 nodes
#define NBLK_B 512       // edge-chunk blocks for bucket count/scatter
#define CHUNK 3125       // N_EDGES / NBLK_B
#define BSTRIDE 1024     // padded stride for bcnt/off tables
#define MAXPT 12         // per-thread reg capacity in CSR build (3072/bucket)

// ---------------- K1: per-block coarse bucket histogram (LDS atomics only) ----------------

__global__ __launch_bounds__(256) void k_bucket_count(const int* __restrict__ dst,
                                                      int* __restrict__ bcnt) {
    __shared__ int h[NBUCK];
    int t = threadIdx.x;
    for (int b = t; b < NBUCK; b += 256) h[b] = 0;
    __syncthreads();
    int base = blockIdx.x * CHUNK, end = base + CHUNK;
#pragma unroll
    for (int it = 0; it < 13; ++it) {
        int i = base + it * 256 + t;
        if (i < end) atomicAdd(&h[dst[i] >> 7], 1);
    }
    __syncthreads();
    for (int b = t; b < NBUCK; b += 256) bcnt[blockIdx.x * BSTRIDE + b] = h[b];
}

// ---------------- K2a: per-bucket column scan over 512 blocks -> off, total ----------------

__global__ __launch_bounds__(256) void k_col_scan(const int* __restrict__ bcnt,
                                                  int* __restrict__ off,
                                                  int* __restrict__ total) {
    __shared__ int v[512];
    __shared__ int ps[256];
    int t = threadIdx.x, b = blockIdx.x;
    v[t]       = bcnt[t * BSTRIDE + b];
    v[t + 256] = bcnt[(t + 256) * BSTRIDE + b];
    __syncthreads();
    int a = v[2 * t], c = v[2 * t + 1];
    ps[t] = a + c;
    __syncthreads();
    for (int o = 1; o < 256; o <<= 1) {
        int u = (t >= o) ? ps[t - o] : 0;
        __syncthreads();
        ps[t] += u;
        __syncthreads();
    }
    int ex = (t > 0) ? ps[t - 1] : 0;  // exclusive prefix (local to bucket)
    off[(2 * t) * BSTRIDE + b]     = ex;
    off[(2 * t + 1) * BSTRIDE + b] = ex + a;
    if (t == 255) total[b] = ps[255];
}

// ---------------- K2b: scan bucket totals -> bucket_start ----------------

__global__ __launch_bounds__(256) void k_bucket_scan(const int* __restrict__ total,
                                                     int* __restrict__ bucket_start,
                                                     int* __restrict__ row_start) {
    __shared__ int ps[256];
    int t = threadIdx.x;
    int v[4];
    int base = t * 4;
#pragma unroll
    for (int q = 0; q < 4; ++q) v[q] = (base + q < NBUCK) ? total[base + q] : 0;
    ps[t] = v[0] + v[1] + v[2] + v[3];
    __syncthreads();
    for (int o = 1; o < 256; o <<= 1) {
        int u = (t >= o) ? ps[t - o] : 0;
        __syncthreads();
        ps[t] += u;
        __syncthreads();
    }
    int run = (t > 0) ? ps[t - 1] : 0;
#pragma unroll
    for (int q = 0; q < 4; ++q) {
        if (base + q <= NBUCK) bucket_start[base + q] = run;
        run += v[q];
    }
    if (t == 0) row_start[N_NODES] = N_EDGES;
}

// ------- K3 fat kernel: blocks [0,512) scatter edges into buckets; rest do h1 = x@W1 -------

__global__ __launch_bounds__(256) void k_scatter_fat(const int* __restrict__ src,
                                                     const int* __restrict__ dst,
                                                     const int* __restrict__ bucket_start,
                                                     const int* __restrict__ off,
                                                     int* __restrict__ tmp,
                                                     const float* __restrict__ x,
                                                     const float* __restrict__ W1,
                                                     float* __restrict__ h1) {
    __shared__ float smem[IN_C * HID_C + 4 * IN_C];  // 34,816 B
    int t = threadIdx.x;
    if (blockIdx.x < NBLK_B) {
        // bucket scatter: write window per (block, bucket) is disjoint
        int* cur = (int*)smem;
        for (int b = t; b < NBUCK; b += 256)
            cur[b] = bucket_start[b] + off[blockIdx.x * BSTRIDE + b];
        __syncthreads();
        int base = blockIdx.x * CHUNK, end = base + CHUNK;
#pragma unroll
        for (int it = 0; it < 13; ++it) {
            int i = base + it * 256 + t;
            if (i < end) {
                int s = src[i], d = dst[i];
                int b = d >> 7;
                int p = atomicAdd(&cur[b], 1);
                tmp[p] = (s << 7) | (d & 127);
            }
        }
    } else {
        // h1 = x @ W1 (no dinv scale; gather1 applies it per-src)
        float* Ws = smem;                 // 8192 floats
        float* xs = smem + IN_C * HID_C;  // 512 floats
        for (int j = t; j < IN_C * HID_C; j += 256) Ws[j] = W1[j];
        int row0 = (blockIdx.x - NBLK_B) * 4;
        xs[t]       = x[row0 * IN_C + t];
        xs[t + 256] = x[row0 * IN_C + t + 256];
        __syncthreads();
        int r = t >> 6, c = t & 63;
        float sum = 0.f;
#pragma unroll
        for (int k = 0; k < IN_C; ++k) sum += xs[r * IN_C + k] * Ws[k * HID_C + c];
        h1[(row0 + r) * HID_C + c] = sum;
    }
}

// ------- K4: per-bucket CSR build (LDS hist + scan + cursors), emits row_start/dinv/eidx -------

__global__ __launch_bounds__(256) void k_csr_build(const int* __restrict__ bucket_start,
                                                   const int* __restrict__ tmp,
                                                   int* __restrict__ row_start,
                                                   int* __restrict__ eidx,
                                                   float* __restrict__ dinv) {
    __shared__ int h[128];
    __shared__ int cur[128];
    int b = blockIdx.x, t = threadIdx.x;
    int e0 = bucket_start[b], e1 = bucket_start[b + 1];
    if (t < 128) h[t] = 0;
    int pk[MAXPT];
#pragma unroll
    for (int k = 0; k < MAXPT; ++k) {
        int i = e0 + k * 256 + t;
        pk[k] = (i < e1) ? tmp[i] : -1;
    }
    __syncthreads();
#pragma unroll
    for (int k = 0; k < MAXPT; ++k)
        if (pk[k] >= 0) atomicAdd(&h[pk[k] & 127], 1);
    for (int i = e0 + MAXPT * 256 + t; i < e1; i += 256)  // safety tail (never expected)
        atomicAdd(&h[tmp[i] & 127], 1);
    __syncthreads();
    int d0 = (t < 128) ? h[t] : 0;
    // inclusive scan over 128 entries
    for (int o = 1; o < 128; o <<= 1) {
        int u = (t >= o && t < 128) ? h[t - o] : 0;
        __syncthreads();
        if (t < 128) h[t] += u;
        __syncthreads();
    }
    int g = b * 128 + t;
    if (t < 128 && g < N_NODES) {
        int ex = h[t] - d0;
        row_start[g] = e0 + ex;
        cur[t]       = e0 + ex;
        dinv[g] = rsqrtf((float)(d0 + 1));  // +1 self loop
    }
    __syncthreads();
#pragma unroll
    for (int k = 0; k < MAXPT; ++k)
        if (pk[k] >= 0) {
            int p = atomicAdd(&cur[pk[k] & 127], 1);
            eidx[p] = pk[k] >> 7;
        }
    for (int i = e0 + MAXPT * 256 + t; i < e1; i += 256) {
        int v = tmp[i];
        int p = atomicAdd(&cur[v & 127], 1);
        eidx[p] = v >> 7;
    }
}

// ------- gather layer 1: a1 = relu(dinv_i*(dinv_i*h1_i + sum_j dinv_j*h1_j) + b1) -------

__global__ __launch_bounds__(256) void k_gather1(const int* __restrict__ row_start,
                                                 const int* __restrict__ eidx,
                                                 const float* __restrict__ h1,
                                                 const float* __restrict__ dinv,
                                                 const float* __restrict__ b1,
                                                 float* __restrict__ a1) {
    int tid  = threadIdx.x;
    int lane = tid & 63;
    int node = blockIdx.x * 4 + (tid >> 6);
    if (node >= N_NODES) return;

    float dn = dinv[node];
    int rs = row_start[node];
    int re = row_start[node + 1];
    float acc = dn * h1[node * HID_C + lane];  // self loop
    int j = rs;
    for (; j + 3 < re; j += 4) {
        int s0 = eidx[j], s1 = eidx[j + 1], s2 = eidx[j + 2], s3 = eidx[j + 3];
        float g0 = dinv[s0], g1 = dinv[s1], g2 = dinv[s2], g3 = dinv[s3];
        float v0 = h1[s0 * HID_C + lane];
        float v1 = h1[s1 * HID_C + lane];
        float v2 = h1[s2 * HID_C + lane];
        float v3 = h1[s3 * HID_C + lane];
        acc += g0 * v0 + g1 * v1 + g2 * v2 + g3 * v3;
    }
    for (; j < re; ++j) acc += dinv[eidx[j]] * h1[eidx[j] * HID_C + lane];

    float v = dn * acc + b1[lane];
    a1[node * HID_C + lane] = fmaxf(v, 0.f);
}

// ---------------- layer 2 GEMM: hs2 = dinv * (a1 @ W2) ----------------

__global__ __launch_bounds__(256) void k_gemm2(const float* __restrict__ a1,
                                               const float* __restrict__ W2,
                                               const float* __restrict__ dinv,
                                               float* __restrict__ hs2) {
    __shared__ float Ws[HID_C * OUT_C];  // 8 KiB
    __shared__ float as[8 * HID_C];      // 2 KiB
    int tid = threadIdx.x;
    for (int j = tid; j < HID_C * OUT_C; j += 256) Ws[j] = W2[j];
    int r = tid >> 5;   // 0..7
    int c = tid & 31;   // 0..31
    int row0 = blockIdx.x * 8;
    as[tid]       = a1[row0 * HID_C + tid];
    as[tid + 256] = a1[row0 * HID_C + tid + 256];
    __syncthreads();
    float sum = 0.f;
#pragma unroll
    for (int k = 0; k < HID_C; ++k) sum += as[r * HID_C + k] * Ws[k * OUT_C + c];
    int row = row0 + r;
    hs2[row * OUT_C + c] = dinv[row] * sum;
}

// ------- gather layer 2 + epilogue: out = dinv*(hs2[i] + sum_j hs2[src_j]) + b2 -------

__global__ __launch_bounds__(256) void k_gather2(const int* __restrict__ row_start,
                                                 const int* __restrict__ eidx,
                                                 const float* __restrict__ hs2,
                                                 const float* __restrict__ dinv,
                                                 const float* __restrict__ b2,
                                                 float* __restrict__ out) {
    int tid  = threadIdx.x;
    int lane = tid & 63;
    int half = lane >> 5;   // 0 or 1
    int c    = lane & 31;
    int node = blockIdx.x * 4 + (tid >> 6);
    if (node >= N_NODES) return;

    int rs = row_start[node];
    int re = row_start[node + 1];
    float acc = (half == 0) ? hs2[node * OUT_C + c] : 0.f;  // self loop
    int j = rs + half;
    for (; j + 3 < re; j += 4) {
        int s0 = eidx[j], s1 = eidx[j + 2];
        float v0 = hs2[s0 * OUT_C + c];
        float v1 = hs2[s1 * OUT_C + c];
        acc += v0 + v1;
    }
    for (; j < re; j += 2) acc += hs2[eidx[j] * OUT_C + c];

    acc += __shfl_xor(acc, 32);
    if (half == 0) out[node * OUT_C + c] = dinv[node] * acc + b2[c];
}

extern "C" void kernel_launch(void* const* d_in, const int* in_sizes, int n_in,
                              void* d_out, int out_size, void* d_ws, size_t ws_size,
                              hipStream_t stream) {
    const float* x  = (const float*)d_in[0];
    const int* ei   = (const int*)d_in[1];   // [2, E]: src then dst
    const float* W1 = (const float*)d_in[2];
    const float* b1 = (const float*)d_in[3];
    const float* W2 = (const float*)d_in[4];
    const float* b2 = (const float*)d_in[5];
    float* out = (float*)d_out;

    const int* src = ei;
    const int* dst = ei + N_EDGES;

    // workspace layout (bytes), total ~62.6 MB
    char* ws = (char*)d_ws;
    int*   row_start    = (int*)(ws + 0);           //   400,128 (N+1 ints)
    float* dinv         = (float*)(ws + 400128);    //   400,128
    int*   bucket_start = (int*)(ws + 800256);      //     4,096
    int*   total        = (int*)(ws + 804352);      //     4,096
    int*   bcnt         = (int*)(ws + 808448);      // 2,097,152
    int*   off          = (int*)(ws + 2905600);     // 2,097,152
    int*   eidx         = (int*)(ws + 5002752);     // 6,400,000
    float* h1           = (float*)(ws + 11402752);  // 25,600,000
    float* a1           = (float*)(ws + 37002752);  // 25,600,000
    int*   tmp          = (int*)(ws + 37002752);    // overlays a1 (dead before gather1 writes a1)
    float* hs2          = h1;                       // reuse (h1 dead after gather1)

    k_bucket_count<<<NBLK_B, 256, 0, stream>>>(dst, bcnt);
    k_col_scan<<<NBUCK, 256, 0, stream>>>(bcnt, off, total);
    k_bucket_scan<<<1, 256, 0, stream>>>(total, bucket_start, row_start);

    k_scatter_fat<<<NBLK_B + N_NODES / 4, 256, 0, stream>>>(src, dst, bucket_start, off,
                                                            tmp, x, W1, h1);
    k_csr_build<<<NBUCK, 256, 0, stream>>>(bucket_start, tmp, row_start, eidx, dinv);

    k_gather1<<<N_NODES / 4, 256, 0, stream>>>(row_start, eidx, h1, dinv, b1, a1);

    k_gemm2<<<N_NODES / 8, 256, 0, stream>>>(a1, W2, dinv, hs2);
    k_gather2<<<N_NODES / 4, 256, 0, stream>>>(row_start, eidx, hs2, dinv, b2, out);
}